// Round 1
// baseline (572.067 us; speedup 1.0000x reference)
//
#include <hip/hip_runtime.h>
#include <hip/hip_bf16.h>
#include <stdint.h>

typedef __bf16 bf16;
typedef bf16 bf16x8 __attribute__((ext_vector_type(8)));
typedef bf16 bf16x4 __attribute__((ext_vector_type(4)));
typedef float floatx4 __attribute__((ext_vector_type(4)));

#define DM   4096
#define NSEQ 2048
#define NH   32
#define DH   128

// ---------- helpers ----------

__device__ __forceinline__ bf16 cvt_bf16(float f) {
  uint32_t u = __builtin_bit_cast(uint32_t, f);
  u += 0x7FFFu + ((u >> 16) & 1u);          // RTNE
  uint16_t h = (uint16_t)(u >> 16);
  return __builtin_bit_cast(bf16, h);
}

// async global->LDS, 16B per lane. LDS dest is wave-uniform base + lane*16;
// our chunk indexing guarantees lane0's pointer is the wave base.
__device__ __forceinline__ void gload_lds16(const bf16* g, bf16* l) {
  __builtin_amdgcn_global_load_lds(
      (__attribute__((address_space(1))) uint32_t*)(uintptr_t)g,
      (__attribute__((address_space(3))) uint32_t*)l,
      16, 0, 0);
}

// ---------- one-time prep kernels ----------

__global__ void cast_bf16_kernel(const float* __restrict__ in, bf16* __restrict__ out, int n) {
  int i = (blockIdx.x * 256 + threadIdx.x) * 4;
  if (i >= n) return;
  float4 v = *(const float4*)&in[i];
  bf16x4 o;
  o[0] = cvt_bf16(v.x); o[1] = cvt_bf16(v.y);
  o[2] = cvt_bf16(v.z); o[3] = cvt_bf16(v.w);
  *(bf16x4*)&out[i] = o;
}

// in [R][C] f32 -> out [C][R] bf16
__global__ void transpose_cast(const float* __restrict__ in, bf16* __restrict__ out, int R, int C) {
  __shared__ bf16 t[32][33];
  int lx = threadIdx.x & 31, ly = threadIdx.x >> 5;   // 32 x 8
  int r0 = blockIdx.y * 32, c0 = blockIdx.x * 32;
  #pragma unroll
  for (int i = 0; i < 4; ++i)
    t[ly + i * 8][lx] = cvt_bf16(in[(size_t)(r0 + ly + i * 8) * C + c0 + lx]);
  __syncthreads();
  #pragma unroll
  for (int i = 0; i < 4; ++i)
    out[(size_t)(c0 + ly + i * 8) * R + r0 + lx] = t[lx][ly + i * 8];
}

// ---------- NT GEMM: C[M,N] = A[M,K] * B[N,K]^T + bias ----------
// MODE 0: f32 out + bias          (final projection)
// MODE 1: bf16 out + bias         (Q projection)
// MODE 3: fused KV: col<128 -> Kb[row][col] (+bk); col>=128 -> Vt[col-128][row] (+bv)

template<int BM, int BN, int MODE>
__global__ __launch_bounds__(256)
void gemm_nt(const bf16* __restrict__ A, const bf16* __restrict__ B,
             const float* __restrict__ bias, const float* __restrict__ bias2,
             float* __restrict__ outf, bf16* __restrict__ outb, bf16* __restrict__ outb2,
             int M, int N, int K)
{
  constexpr int BK = 32;
  constexpr int TM = BM / 2, TN = BN / 2;
  constexpr int MT = TM / 16, NT = TN / 16;
  __shared__ __align__(16) bf16 As[BM * BK];
  __shared__ __align__(16) bf16 Bs[BN * BK];
  const int tid  = threadIdx.x;
  const int lane = tid & 63;
  const int wave = tid >> 6;
  const int quad = lane >> 4;
  const int l15  = lane & 15;
  const int wm = wave >> 1, wn = wave & 1;
  const int m0 = blockIdx.y * BM;
  const int n0 = blockIdx.x * BN;

  floatx4 acc[MT][NT] = {};

  for (int k0 = 0; k0 < K; k0 += BK) {
    __syncthreads();
    #pragma unroll
    for (int i = 0; i < BM / 64; ++i) {
      int c = i * 256 + tid;
      int r = c >> 2, kc = (c & 3) ^ (r & 3);          // XOR-swizzled 16B chunks
      gload_lds16(A + (size_t)(m0 + r) * K + k0 + kc * 8, &As[c * 8]);
    }
    #pragma unroll
    for (int i = 0; i < BN / 64; ++i) {
      int c = i * 256 + tid;
      int r = c >> 2, kc = (c & 3) ^ (r & 3);
      gload_lds16(B + (size_t)(n0 + r) * K + k0 + kc * 8, &Bs[c * 8]);
    }
    __syncthreads();

    bf16x8 af[MT], bfr[NT];
    #pragma unroll
    for (int mt = 0; mt < MT; ++mt) {
      int r = wm * TM + mt * 16 + l15;
      af[mt] = *(const bf16x8*)&As[r * BK + ((quad ^ (r & 3)) * 8)];
    }
    #pragma unroll
    for (int nt = 0; nt < NT; ++nt) {
      int r = wn * TN + nt * 16 + l15;
      bfr[nt] = *(const bf16x8*)&Bs[r * BK + ((quad ^ (r & 3)) * 8)];
    }
    #pragma unroll
    for (int mt = 0; mt < MT; ++mt)
      #pragma unroll
      for (int nt = 0; nt < NT; ++nt)
        acc[mt][nt] = __builtin_amdgcn_mfma_f32_16x16x32_bf16(af[mt], bfr[nt], acc[mt][nt], 0, 0, 0);
  }

  #pragma unroll
  for (int mt = 0; mt < MT; ++mt) {
    #pragma unroll
    for (int nt = 0; nt < NT; ++nt) {
      int col = n0 + wn * TN + nt * 16 + l15;
      #pragma unroll
      for (int r = 0; r < 4; ++r) {
        int row = m0 + wm * TM + mt * 16 + quad * 4 + r;
        float v = acc[mt][nt][r];
        if constexpr (MODE == 0) {
          outf[(size_t)row * N + col] = v + bias[col];
        } else if constexpr (MODE == 1) {
          outb[(size_t)row * N + col] = cvt_bf16(v + bias[col]);
        } else {
          if (col < DH) outb [(size_t)row * DH + col]        = cvt_bf16(v + bias[col]);
          else          outb2[(size_t)(col - DH) * M + row]  = cvt_bf16(v + bias2[col - DH]);
        }
      }
    }
  }
}

// ---------- flash MQA attention ----------
// Qb [NSEQ][DM] bf16 (head h = cols h*128..), Kb [NSEQ][DH] bf16, Vt [DH][NSEQ] bf16
// Ob [NSEQ][DM] bf16. Grid: (NSEQ/128, NH). Block 256 = 4 waves, 32 q-rows/wave.

__global__ __launch_bounds__(256, 2)
void flash_mqa(const bf16* __restrict__ Qb, const bf16* __restrict__ Kb,
               const bf16* __restrict__ Vt, bf16* __restrict__ Ob)
{
  constexpr int KT  = 128;
  constexpr int PLD = 136;                       // padded P row (+16B)
  __shared__ __align__(16) bf16 KV[KT * DH];     // swizzled; holds K then V
  __shared__ __align__(16) bf16 Pl[4][32 * PLD];
  const int tid = threadIdx.x, lane = tid & 63, wave = tid >> 6;
  const int quad = lane >> 4, l15 = lane & 15;
  const int h  = blockIdx.y;
  const int q0 = blockIdx.x * 128 + wave * 32;

  bf16x8 qf[2][4];
  #pragma unroll
  for (int mt = 0; mt < 2; ++mt)
    #pragma unroll
    for (int kf = 0; kf < 4; ++kf)
      qf[mt][kf] = *(const bf16x8*)&Qb[(size_t)(q0 + mt * 16 + l15) * DM + h * DH + kf * 32 + quad * 8];

  floatx4 o[2][8] = {};
  float mrow[2][4], lrow[2][4];
  #pragma unroll
  for (int mt = 0; mt < 2; ++mt)
    #pragma unroll
    for (int r = 0; r < 4; ++r) { mrow[mt][r] = -1e30f; lrow[mt][r] = 0.f; }

  const float SCL = 0.08838834764831845f * 1.44269504088896340f;  // 1/sqrt(128) * log2(e)

  for (int kt = 0; kt < NSEQ; kt += KT) {
    __syncthreads();
    #pragma unroll
    for (int i = 0; i < 8; ++i) {                 // stage K tile (async, swizzled)
      int c = i * 256 + tid;
      int n = c >> 4, kc = (c & 15) ^ (n & 15);
      gload_lds16(Kb + (size_t)(kt + n) * DH + kc * 8, &KV[c * 8]);
    }
    __syncthreads();

    // S = Q K^T
    floatx4 s[2][8] = {};
    #pragma unroll
    for (int nt = 0; nt < 8; ++nt) {
      bf16x8 kfr[4];
      #pragma unroll
      for (int kf = 0; kf < 4; ++kf)
        kfr[kf] = *(const bf16x8*)&KV[(nt * 16 + l15) * DH + (((kf * 4 + quad) ^ l15) * 8)];
      #pragma unroll
      for (int mt = 0; mt < 2; ++mt)
        #pragma unroll
        for (int kf = 0; kf < 4; ++kf)
          s[mt][nt] = __builtin_amdgcn_mfma_f32_16x16x32_bf16(qf[mt][kf], kfr[kf], s[mt][nt], 0, 0, 0);
    }

    // online softmax (exp2 domain), P -> LDS (per-wave region)
    float alpha[2][4];
    #pragma unroll
    for (int mt = 0; mt < 2; ++mt) {
      float tmax[4] = {-1e30f, -1e30f, -1e30f, -1e30f};
      #pragma unroll
      for (int nt = 0; nt < 8; ++nt)
        #pragma unroll
        for (int r = 0; r < 4; ++r) {
          float sv = s[mt][nt][r] * SCL;
          s[mt][nt][r] = sv;
          tmax[r] = fmaxf(tmax[r], sv);
        }
      #pragma unroll
      for (int off = 1; off < 16; off <<= 1)
        #pragma unroll
        for (int r = 0; r < 4; ++r)
          tmax[r] = fmaxf(tmax[r], __shfl_xor(tmax[r], off, 64));
      #pragma unroll
      for (int r = 0; r < 4; ++r) {
        float mnew = fmaxf(mrow[mt][r], tmax[r]);
        alpha[mt][r] = exp2f(mrow[mt][r] - mnew);
        mrow[mt][r] = mnew;
      }
      float rsum[4] = {0.f, 0.f, 0.f, 0.f};
      #pragma unroll
      for (int nt = 0; nt < 8; ++nt)
        #pragma unroll
        for (int r = 0; r < 4; ++r) {
          float p = exp2f(s[mt][nt][r] - mrow[mt][r]);
          s[mt][nt][r] = p;
          rsum[r] += p;
        }
      #pragma unroll
      for (int off = 1; off < 16; off <<= 1)
        #pragma unroll
        for (int r = 0; r < 4; ++r)
          rsum[r] += __shfl_xor(rsum[r], off, 64);
      #pragma unroll
      for (int r = 0; r < 4; ++r)
        lrow[mt][r] = lrow[mt][r] * alpha[mt][r] + rsum[r];
      #pragma unroll
      for (int dt = 0; dt < 8; ++dt)
        #pragma unroll
        for (int r = 0; r < 4; ++r)
          o[mt][dt][r] *= alpha[mt][r];
      #pragma unroll
      for (int nt = 0; nt < 8; ++nt)
        #pragma unroll
        for (int r = 0; r < 4; ++r)
          Pl[wave][(mt * 16 + quad * 4 + r) * PLD + nt * 16 + l15] = cvt_bf16(s[mt][nt][r]);
    }

    __syncthreads();                               // everyone done with K
    #pragma unroll
    for (int i = 0; i < 8; ++i) {                  // stage V tile (async, swizzled)
      int c = i * 256 + tid;
      int n = c >> 4, kc = (c & 15) ^ (n & 15);
      gload_lds16(Vt + (size_t)n * NSEQ + kt + kc * 8, &KV[c * 8]);
    }
    __syncthreads();

    // O += P V  (A = P from LDS in A-layout, B = V^T rows)
    bf16x8 pf[2][4];
    #pragma unroll
    for (int mt = 0; mt < 2; ++mt)
      #pragma unroll
      for (int kf = 0; kf < 4; ++kf)
        pf[mt][kf] = *(const bf16x8*)&Pl[wave][(mt * 16 + l15) * PLD + kf * 32 + quad * 8];
    #pragma unroll
    for (int dt = 0; dt < 8; ++dt) {
      bf16x8 vf[4];
      #pragma unroll
      for (int kf = 0; kf < 4; ++kf)
        vf[kf] = *(const bf16x8*)&KV[(dt * 16 + l15) * DH + (((kf * 4 + quad) ^ l15) * 8)];
      #pragma unroll
      for (int mt = 0; mt < 2; ++mt)
        #pragma unroll
        for (int kf = 0; kf < 4; ++kf)
          o[mt][dt] = __builtin_amdgcn_mfma_f32_16x16x32_bf16(pf[mt][kf], vf[kf], o[mt][dt], 0, 0, 0);
    }
  }

  #pragma unroll
  for (int mt = 0; mt < 2; ++mt) {
    float inv[4];
    #pragma unroll
    for (int r = 0; r < 4; ++r) inv[r] = 1.0f / lrow[mt][r];
    #pragma unroll
    for (int dt = 0; dt < 8; ++dt) {
      int col = h * DH + dt * 16 + l15;
      #pragma unroll
      for (int r = 0; r < 4; ++r) {
        int row = q0 + mt * 16 + quad * 4 + r;
        Ob[(size_t)row * DM + col] = cvt_bf16(o[mt][dt][r] * inv[r]);
      }
    }
  }
}

// ---------- launch ----------

extern "C" void kernel_launch(void* const* d_in, const int* in_sizes, int n_in,
                              void* d_out, int out_size, void* d_ws, size_t ws_size,
                              hipStream_t stream) {
  (void)in_sizes; (void)n_in; (void)out_size;
  const float* x  = (const float*)d_in[0];
  const float* Wq = (const float*)d_in[1];
  const float* bq = (const float*)d_in[2];
  const float* Wk = (const float*)d_in[3];
  const float* bk = (const float*)d_in[4];
  const float* Wv = (const float*)d_in[5];
  const float* bv = (const float*)d_in[6];
  const float* Wo = (const float*)d_in[7];
  const float* bo = (const float*)d_in[8];
  float* out = (float*)d_out;

  char* ws = (char*)d_ws;
  size_t off = 0;
  auto alloc = [&](size_t bytes) {
    char* p = ws + off;
    off += (bytes + 255) & ~(size_t)255;
    return p;
  };
  bf16* xb   = (bf16*)alloc((size_t)NSEQ * DM * 2);   // x bf16; later reused as Ob
  bf16* WT   = (bf16*)alloc((size_t)DM * DM * 2);     // WqT, then WoT
  bf16* WkvT = (bf16*)alloc((size_t)2 * DH * DM * 2); // [256][4096]
  bf16* Qb   = (bf16*)alloc((size_t)NSEQ * DM * 2);
  bf16* Kb   = (bf16*)alloc((size_t)NSEQ * DH * 2);
  bf16* Vt   = (bf16*)alloc((size_t)DH * NSEQ * 2);
  bf16* Ob   = xb;                                    // alias: x dead after KV GEMM
  if (off > ws_size) return;                          // insufficient scratch — bail loudly

  cast_bf16_kernel<<<NSEQ * DM / 1024, 256, 0, stream>>>(x, xb, NSEQ * DM);

  transpose_cast<<<dim3(DM / 32, DM / 32), 256, 0, stream>>>(Wq, WT, DM, DM);
  gemm_nt<128, 128, 1><<<dim3(DM / 128, NSEQ / 128), 256, 0, stream>>>(
      xb, WT, bq, nullptr, nullptr, Qb, nullptr, NSEQ, DM, DM);

  transpose_cast<<<dim3(DH / 32, DM / 32), 256, 0, stream>>>(Wk, WkvT, DM, DH);
  transpose_cast<<<dim3(DH / 32, DM / 32), 256, 0, stream>>>(Wv, WkvT + (size_t)DH * DM, DM, DH);
  gemm_nt<64, 64, 3><<<dim3(256 / 64, NSEQ / 64), 256, 0, stream>>>(
      xb, WkvT, bk, bv, nullptr, Kb, Vt, NSEQ, 2 * DH, DM);

  transpose_cast<<<dim3(DM / 32, DM / 32), 256, 0, stream>>>(Wo, WT, DM, DM);

  flash_mqa<<<dim3(NSEQ / 128, NH), 256, 0, stream>>>(Qb, Kb, Vt, Ob);

  gemm_nt<128, 128, 0><<<dim3(DM / 128, NSEQ / 128), 256, 0, stream>>>(
      Ob, WT, bo, nullptr, out, nullptr, nullptr, NSEQ, DM, DM);
}